// Round 9
// baseline (2163.941 us; speedup 1.0000x reference)
//
#include <hip/hip_runtime.h>
#include <math.h>

#define HH 512
#define WW 1024
#define HWSZ (HH*WW)
#define BB 4
#define TY 8
#define NP (TY/2)
#define KSIG 11.541560327111707
#define DD_OFF (BB*3*HWSZ)

typedef float v2f __attribute__((ext_vector_type(2)));

// One column-group for one source row, evaluated against TY output rows in
// PAIRS (packed f32). Accumulators are kernel-scope locals touched only with
// compile-time indices (no pointer passing -> SROA-safe; R8 lesson).
// Dead (row,offset) halves are baked into the table as (D=1e30, C=+inf):
// w = rcp(inf) = 0 exactly, circle test r>=1e30 false -> branchless masking.
#define GROUP_EVAL(NJ, ...) do {                                              \
    constexpr int rxs[NJ] = { __VA_ARGS__ };                                  \
    float d[NJ], i0[NJ], i1[NJ], i2[NJ];                                      \
    _Pragma("unroll")                                                         \
    for (int j = 0; j < NJ; ++j) {                                            \
        const int rx = rxs[j];                                                \
        if (edge) {                                                           \
            const int col = x + rx;                                           \
            const bool valid = (unsigned)col < (unsigned)WW;                  \
            const int cc  = col < 0 ? 0 : (col > WW-1 ? WW-1 : col);          \
            const int cof = cc - x;              /* clamped (safe) offset */  \
            float dv = d_ = pd[cof];                                          \
            d[j]  = valid ? dv : 0.0f;    /* OOB: w<=3.4e-4, no circle */     \
            i0[j] = p0[cof]; i1[j] = p1[cof]; i2[j] = p2[cof];                \
        } else {                                                              \
            d[j] = pd[rx]; i0[j] = p0[rx]; i1[j] = p1[rx]; i2[j] = p2[rx];    \
        }                                                                     \
    }                                                                         \
    float r[NJ], rr[NJ], rc[NJ], di[NJ];                                      \
    _Pragma("unroll")                                                         \
    for (int j = 0; j < NJ; ++j) {                                            \
        r[j]  = fabsf(d[j]);                                                  \
        rr[j] = fmaxf(d[j]*d[j], 1.0f);                                       \
        rc[j] = rr[j] * __builtin_amdgcn_exp2f(r[j] * (float)(-KSIG));        \
        di[j] = truncf(d[j]);                /* == (float)(int)defocus */     \
    }                                                                         \
    _Pragma("unroll")                                                         \
    for (int p = 0; p < NP; ++p) {                                            \
        const int m = ryy - 2*p;             /* rows |m|, |m-1| */            \
        if (m < -6 || m > 7) continue;       /* uniform: pair fully dead */   \
        const float4* __restrict__ prow = (const float4*)T4[m + 6];           \
        _Pragma("unroll")                                                     \
        for (int j = 0; j < NJ; ++j) {                                        \
            const int ax = rxs[j] < 0 ? -rxs[j] : rxs[j];                     \
            const float4 t = prow[ax];       /* ds_read_b128 broadcast */     \
            v2f den = (v2f){t.z, t.w} * rc[j] + rr[j];   /* v_pk_fma_f32 */   \
            v2f w = { __builtin_amdgcn_rcpf(den.x),                           \
                      __builtin_amdgcn_rcpf(den.y) };                         \
            aW[p] += w;                      /* v_pk_add_f32 */               \
            aR[p] += w * i0[j];              /* v_pk_fma_f32 */               \
            aG[p] += w * i1[j];                                               \
            aB[p] += w * i2[j];                                               \
            v2f cand = { r[j] >= t.x ? di[j] : -1e30f,                        \
                         r[j] >= t.y ? di[j] : -1e30f };                      \
            aD[p] = __builtin_elementwise_max(aD[p], cand);                   \
        }                                                                     \
    }                                                                         \
} while (0)

__global__ __launch_bounds__(256, 4)
void bokeh_kernel(const float* __restrict__ img,
                  const float* __restrict__ defo,
                  float* __restrict__ out)
{
    // T4[m+6][ax] = (D(|m|,ax), D(|m-1|,ax), C(|m|,ax), C(|m-1|,ax)).
    // D = fl32(sqrt(ay^2+ax^2)) correctly rounded (fp64), C = 2^(K*D).
    // Dead halves (ay>6 or ay^2+ax^2>49): (1e30, +inf) -> contribute nothing.
    __shared__ float4 T4[14][7];
    {
        const int t = threadIdx.x;
        if (t < 14*7) {
            const int mi = t / 7, ax = t - mi*7;
            const int m  = mi - 6;
            const int a0 = m < 0 ? -m : m;
            const int a1 = (m-1) < 0 ? -(m-1) : (m-1);
            float D0 = 1e30f, C0 = __builtin_inff();
            float D1 = 1e30f, C1 = __builtin_inff();
            if (a0 <= 6 && a0*a0 + ax*ax <= 49) {
                D0 = (float)sqrt((double)(a0*a0 + ax*ax));
                C0 = (float)exp2((double)D0 * KSIG);
            }
            if (a1 <= 6 && a1*a1 + ax*ax <= 49) {
                D1 = (float)sqrt((double)(a1*a1 + ax*ax));
                C1 = (float)exp2((double)D1 * KSIG);
            }
            T4[mi][ax] = make_float4(D0, D1, C0, C1);
        }
    }
    __syncthreads();

    const int lane = threadIdx.x & 63;
    const int wv   = threadIdx.x >> 6;
    const int bx   = blockIdx.x;
    const int x    = bx*64 + lane;                 // lane = x -> coalesced
    const int y0   = blockIdx.y*(4*TY) + wv*TY;    // TY output rows per thread
    const int b    = blockIdx.z;
    const bool edge = (bx == 0) || (bx == WW/64 - 1);   // wave-uniform

    const float* __restrict__ dP = defo + (size_t)b*HWSZ;
    const float* __restrict__ c0 = img + (size_t)(b*3+0)*HWSZ;
    const float* __restrict__ c1 = img + (size_t)(b*3+1)*HWSZ;
    const float* __restrict__ c2 = img + (size_t)(b*3+2)*HWSZ;

    v2f aW[NP], aR[NP], aG[NP], aB[NP], aD[NP];
#pragma unroll
    for (int p=0;p<NP;++p){
        aW[p]=(v2f){0.f,0.f}; aR[p]=(v2f){0.f,0.f}; aG[p]=(v2f){0.f,0.f};
        aB[p]=(v2f){0.f,0.f}; aD[p]=(v2f){-1e30f,-1e30f};
    }
    float d_;   // dummy sink used by macro's edge path (keeps macro simple)

#pragma unroll 1
    for (int ryy = -6; ryy <= TY+5; ++ryy) {       // source rows (runtime loop)
        const int sy = y0 + ryy;
        if ((unsigned)sy >= (unsigned)HH) continue;    // uniform (zero pad)
        const int rb = sy*WW + x;
        const float* __restrict__ pd = dP + rb;
        const float* __restrict__ p0 = c0 + rb;
        const float* __restrict__ p1 = c1 + rb;
        const float* __restrict__ p2 = c2 + rb;
        GROUP_EVAL(5, -6,-5,-4,-3,-2);
        GROUP_EVAL(5, -1, 0, 1, 2, 3);
        GROUP_EVAL(3,  4, 5, 6);
    }
    (void)d_;

#pragma unroll
    for (int p=0;p<NP;++p) {
        const float invx = __builtin_amdgcn_rcpf(aW[p].x);  // aW >= ~0.0139
        const float invy = __builtin_amdgcn_rcpf(aW[p].y);
        const int yA = y0 + 2*p, yB = yA + 1;
        const size_t oA = (size_t)yA*WW + x, oB = (size_t)yB*WW + x;
        out[(size_t)(b*3+0)*HWSZ + oA] = aR[p].x*invx;
        out[(size_t)(b*3+1)*HWSZ + oA] = aG[p].x*invx;
        out[(size_t)(b*3+2)*HWSZ + oA] = aB[p].x*invx;
        out[DD_OFF + (size_t)b*HWSZ + oA] = aD[p].x;
        out[(size_t)(b*3+0)*HWSZ + oB] = aR[p].y*invy;
        out[(size_t)(b*3+1)*HWSZ + oB] = aG[p].y*invy;
        out[(size_t)(b*3+2)*HWSZ + oB] = aB[p].y*invy;
        out[DD_OFF + (size_t)b*HWSZ + oB] = aD[p].y;
    }
}

extern "C" void kernel_launch(void* const* d_in, const int* in_sizes, int n_in,
                              void* d_out, int out_size, void* d_ws, size_t ws_size,
                              hipStream_t stream)
{
    const float* img  = (const float*)d_in[0];
    const float* defo = (const float*)d_in[1];
    float* out = (float*)d_out;
    bokeh_kernel<<<dim3(WW/64, HH/(4*TY), BB), dim3(256,1,1), 0, stream>>>(img, defo, out);
}

// Round 10
// 167.042 us; speedup vs baseline: 12.9545x; 12.9545x over previous
//
#include <hip/hip_runtime.h>
#include <math.h>

#define HH 512
#define WW 1024
#define HWSZ (HH*WW)
#define BB 4
#define KSIG 11.541560327111707
#define DD_OFF (BB*3*HWSZ)

typedef float v2f __attribute__((ext_vector_type(2)));

// ---- one pair-eval: output rows (2P, 2P+1) vs current column; MI = table row
// (compile-time) -> ds_read_b128 with immediate offset, wave-uniform broadcast.
#define PEVAL(P, MI) {                                                        \
    const float4 t = tp[(MI)*7];           /* (D0,D1,C0,C1) */                \
    v2f den = (v2f){t.z, t.w} * rc + rr;   /* v_pk_fma_f32 */                 \
    v2f w = { __builtin_amdgcn_rcpf(den.x),                                   \
              __builtin_amdgcn_rcpf(den.y) };                                 \
    aW##P += w;                                                               \
    aR##P += w * v0;  aG##P += w * v1;  aB##P += w * v2;                      \
    v2f cand = { r >= t.x ? di : -1e30f,                                      \
                 r >= t.y ? di : -1e30f };                                    \
    aD##P = __builtin_elementwise_max(aD##P, cand);                           \
}

#define COLOFF(J)                                                             \
    if (edge) {                                                               \
        const int col = x + (J) - 6;                                          \
        vld = (unsigned)col < (unsigned)WW;                                   \
        const int cc = col < 0 ? 0 : (col > WW-1 ? WW-1 : col);               \
        off = cc - x;                      /* clamped (safe) offset */        \
    } else { off = (J) - 6; vld = true; }

// ---- one source row (compile-time RYY): runtime 13-column loop (kept rolled
// for I-cache), prefetch-1 rotation, then the site's valid pair-evals.
#define ROW_SITE(RYY, ...) {                                                  \
    const int sy = y0 + (RYY);                                                \
    if ((unsigned)sy < (unsigned)HH) {     /* uniform; skip = zero pad */     \
        const int rb = sy*WW + x;                                             \
        const float* __restrict__ pd = dP + rb;                               \
        const float* __restrict__ p0 = c0 + rb;                               \
        const float* __restrict__ p1 = c1 + rb;                               \
        const float* __restrict__ p2 = c2 + rb;                               \
        int off; bool vld;                                                    \
        COLOFF(0)                                                             \
        float dcur = pd[off], c0v = p0[off], c1v = p1[off], c2v = p2[off];    \
        if (!vld) dcur = 0.0f;             /* OOB col: w<=3.4e-4, no circle */\
        _Pragma("nounroll")                                                   \
        for (int j = 0; j < 13; ++j) {                                        \
            const int jn = j < 12 ? j + 1 : 12;                               \
            COLOFF(jn)                                                        \
            float dn = pd[off], n0 = p0[off], n1 = p1[off], n2 = p2[off];     \
            if (!vld) dn = 0.0f;                                              \
            const float v0 = c0v, v1 = c1v, v2 = c2v;                         \
            const float r  = fabsf(dcur);                                     \
            const float rr = fmaxf(dcur*dcur, 1.0f);                          \
            const float rc = rr * __builtin_amdgcn_exp2f(r*(float)(-KSIG));   \
            const float di = truncf(dcur); /* == (float)(int)defocus */       \
            const int ax = j < 6 ? 6 - j : j - 6;                             \
            const float4* __restrict__ tp = (const float4*)T4 + ax;           \
            __VA_ARGS__                                                       \
            dcur = dn; c0v = n0; c1v = n1; c2v = n2;                          \
        }                                                                     \
    }                                                                         \
}

#define WOUT(P) {                                                             \
    const float ix = __builtin_amdgcn_rcpf(aW##P.x);  /* aW >= ~0.01 */       \
    const float iy = __builtin_amdgcn_rcpf(aW##P.y);                          \
    const int yA = y0 + 2*(P), yB = yA + 1;                                   \
    const size_t oA = (size_t)yA*WW + x, oB = (size_t)yB*WW + x;              \
    out[(size_t)(b*3+0)*HWSZ + oA] = aR##P.x*ix;                              \
    out[(size_t)(b*3+1)*HWSZ + oA] = aG##P.x*ix;                              \
    out[(size_t)(b*3+2)*HWSZ + oA] = aB##P.x*ix;                              \
    out[DD_OFF + (size_t)b*HWSZ + oA] = aD##P.x;                              \
    out[(size_t)(b*3+0)*HWSZ + oB] = aR##P.y*iy;                              \
    out[(size_t)(b*3+1)*HWSZ + oB] = aG##P.y*iy;                              \
    out[(size_t)(b*3+2)*HWSZ + oB] = aB##P.y*iy;                              \
    out[DD_OFF + (size_t)b*HWSZ + oB] = aD##P.y;                              \
}

__global__ __launch_bounds__(256, 4)
void bokeh_kernel(const float* __restrict__ img,
                  const float* __restrict__ defo,
                  float* __restrict__ out)
{
    // T4[m+6][ax] = (D(|m|,ax), D(|m-1|,ax), C(|m|,ax), C(|m-1|,ax)).
    // D = fl32(sqrt(ay^2+ax^2)) correctly rounded (fp64), C = 2^(K*D).
    // Dead halves (ay>6 or ay^2+ax^2>49): (1e30, +inf) -> w=0, never in-circle.
    __shared__ float4 T4[14][7];
    {
        const int t = threadIdx.x;
        if (t < 14*7) {
            const int mi = t / 7, ax = t - mi*7;
            const int m  = mi - 6;
            const int a0 = m < 0 ? -m : m;
            const int a1 = (m-1) < 0 ? -(m-1) : (m-1);
            float D0 = 1e30f, C0 = __builtin_inff();
            float D1 = 1e30f, C1 = __builtin_inff();
            if (a0 <= 6 && a0*a0 + ax*ax <= 49) {
                D0 = (float)sqrt((double)(a0*a0 + ax*ax));
                C0 = (float)exp2((double)D0 * KSIG);
            }
            if (a1 <= 6 && a1*a1 + ax*ax <= 49) {
                D1 = (float)sqrt((double)(a1*a1 + ax*ax));
                C1 = (float)exp2((double)D1 * KSIG);
            }
            T4[mi][ax] = make_float4(D0, D1, C0, C1);
        }
    }
    __syncthreads();

    const int lane = threadIdx.x & 63;
    const int wv   = threadIdx.x >> 6;
    const int bx   = blockIdx.x;
    const int x    = bx*64 + lane;                 // lane = x -> coalesced
    const int y0   = blockIdx.y*32 + wv*8;         // 8 output rows per thread
    const int b    = blockIdx.z;
    const bool edge = (bx == 0) || (bx == WW/64 - 1);   // wave-uniform

    const float* __restrict__ dP = defo + (size_t)b*HWSZ;
    const float* __restrict__ c0 = img + (size_t)(b*3+0)*HWSZ;
    const float* __restrict__ c1 = img + (size_t)(b*3+1)*HWSZ;
    const float* __restrict__ c2 = img + (size_t)(b*3+2)*HWSZ;

    // named accumulators only -- no arrays, no address-taken (R8/R9 lesson)
    v2f aW0={0,0}, aW1={0,0}, aW2={0,0}, aW3={0,0};
    v2f aR0={0,0}, aR1={0,0}, aR2={0,0}, aR3={0,0};
    v2f aG0={0,0}, aG1={0,0}, aG2={0,0}, aG3={0,0};
    v2f aB0={0,0}, aB1={0,0}, aB2={0,0}, aB3={0,0};
    v2f aD0={-1e30f,-1e30f}, aD1={-1e30f,-1e30f};
    v2f aD2={-1e30f,-1e30f}, aD3={-1e30f,-1e30f};

    ROW_SITE(-6, PEVAL(0,0))
    ROW_SITE(-5, PEVAL(0,1))
    ROW_SITE(-4, PEVAL(0,2)  PEVAL(1,0))
    ROW_SITE(-3, PEVAL(0,3)  PEVAL(1,1))
    ROW_SITE(-2, PEVAL(0,4)  PEVAL(1,2)  PEVAL(2,0))
    ROW_SITE(-1, PEVAL(0,5)  PEVAL(1,3)  PEVAL(2,1))
    ROW_SITE( 0, PEVAL(0,6)  PEVAL(1,4)  PEVAL(2,2)  PEVAL(3,0))
    ROW_SITE( 1, PEVAL(0,7)  PEVAL(1,5)  PEVAL(2,3)  PEVAL(3,1))
    ROW_SITE( 2, PEVAL(0,8)  PEVAL(1,6)  PEVAL(2,4)  PEVAL(3,2))
    ROW_SITE( 3, PEVAL(0,9)  PEVAL(1,7)  PEVAL(2,5)  PEVAL(3,3))
    ROW_SITE( 4, PEVAL(0,10) PEVAL(1,8)  PEVAL(2,6)  PEVAL(3,4))
    ROW_SITE( 5, PEVAL(0,11) PEVAL(1,9)  PEVAL(2,7)  PEVAL(3,5))
    ROW_SITE( 6, PEVAL(0,12) PEVAL(1,10) PEVAL(2,8)  PEVAL(3,6))
    ROW_SITE( 7, PEVAL(0,13) PEVAL(1,11) PEVAL(2,9)  PEVAL(3,7))
    ROW_SITE( 8,             PEVAL(1,12) PEVAL(2,10) PEVAL(3,8))
    ROW_SITE( 9,             PEVAL(1,13) PEVAL(2,11) PEVAL(3,9))
    ROW_SITE(10,                         PEVAL(2,12) PEVAL(3,10))
    ROW_SITE(11,                         PEVAL(2,13) PEVAL(3,11))
    ROW_SITE(12,                                     PEVAL(3,12))
    ROW_SITE(13,                                     PEVAL(3,13))

    WOUT(0) WOUT(1) WOUT(2) WOUT(3)
}

extern "C" void kernel_launch(void* const* d_in, const int* in_sizes, int n_in,
                              void* d_out, int out_size, void* d_ws, size_t ws_size,
                              hipStream_t stream)
{
    const float* img  = (const float*)d_in[0];
    const float* defo = (const float*)d_in[1];
    float* out = (float*)d_out;
    bokeh_kernel<<<dim3(WW/64, HH/32, BB), dim3(256,1,1), 0, stream>>>(img, defo, out);
}